// Round 1
// baseline (319.473 us; speedup 1.0000x reference)
//
#include <hip/hip_runtime.h>

// QPChargeNormalization: per batch row b (n = 8192 = 4096 iso + 4096 aniso):
//   u/2 = (sum(charge[b]) - q.c) / (q.q);  x = c + (u/2) q
// One block (256 threads) per row; payload held in registers across the
// reduction so the epilogue does zero global re-reads. Memory-bound:
// ~407 MB total traffic -> ~65 us roofline at 6.3 TB/s.

#define HALF_N 4096   // elements per row in each of the iso/aniso halves
#define BLOCK  256

__global__ __launch_bounds__(BLOCK, 4) void qp_charge_norm_kernel(
    const float* __restrict__ c_iso,
    const float* __restrict__ c_aniso,
    const float* __restrict__ q_iso,
    const float* __restrict__ q_aniso,
    const float* __restrict__ charge,   // [B, 256]
    float* __restrict__ out,            // [B*4096 iso][B*4096 aniso]
    int B)
{
    const int b   = blockIdx.x;
    const int tid = threadIdx.x;

    const float4* ci = (const float4*)(c_iso   + (size_t)b * HALF_N);
    const float4* ca = (const float4*)(c_aniso + (size_t)b * HALF_N);
    const float4* qi = (const float4*)(q_iso   + (size_t)b * HALF_N);
    const float4* qa = (const float4*)(q_aniso + (size_t)b * HALF_N);

    // Each thread: 4 float4 from iso half + 4 from aniso half, per array.
    // float4 index j*256 + tid  -> lane-contiguous 16B accesses (coalesced).
    float4 cv[8], qv[8];
#pragma unroll
    for (int j = 0; j < 4; ++j) {
        cv[j]     = ci[j * BLOCK + tid];
        qv[j]     = qi[j * BLOCK + tid];
        cv[j + 4] = ca[j * BLOCK + tid];
        qv[j + 4] = qa[j * BLOCK + tid];
    }

    float qc = 0.0f, qq = 0.0f;
#pragma unroll
    for (int j = 0; j < 8; ++j) {
        qc += qv[j].x * cv[j].x + qv[j].y * cv[j].y
            + qv[j].z * cv[j].z + qv[j].w * cv[j].w;
        qq += qv[j].x * qv[j].x + qv[j].y * qv[j].y
            + qv[j].z * qv[j].z + qv[j].w * qv[j].w;
    }
    // charge: exactly one element per thread (256 per row)
    float Qp = charge[(size_t)b * 256 + tid];

    // wave-64 butterfly-ish down-shuffle reduce
#pragma unroll
    for (int off = 32; off > 0; off >>= 1) {
        qc += __shfl_down(qc, off, 64);
        qq += __shfl_down(qq, off, 64);
        Qp += __shfl_down(Qp, off, 64);
    }

    __shared__ float s_qc[4], s_qq[4], s_Q[4];
    __shared__ float s_half_u;
    const int wave = tid >> 6;
    const int lane = tid & 63;
    if (lane == 0) { s_qc[wave] = qc; s_qq[wave] = qq; s_Q[wave] = Qp; }
    __syncthreads();
    if (tid == 0) {
        float tqc = s_qc[0] + s_qc[1] + s_qc[2] + s_qc[3];
        float tqq = s_qq[0] + s_qq[1] + s_qq[2] + s_qq[3];
        float tQ  = s_Q[0]  + s_Q[1]  + s_Q[2]  + s_Q[3];
        s_half_u = (tQ - tqc) / tqq;   // = u/2
    }
    __syncthreads();
    const float h = s_half_u;

    float4* oi = (float4*)(out + (size_t)b * HALF_N);
    float4* oa = (float4*)(out + (size_t)B * HALF_N + (size_t)b * HALF_N);
#pragma unroll
    for (int j = 0; j < 4; ++j) {
        float4 r;
        r.x = cv[j].x + h * qv[j].x;
        r.y = cv[j].y + h * qv[j].y;
        r.z = cv[j].z + h * qv[j].z;
        r.w = cv[j].w + h * qv[j].w;
        oi[j * BLOCK + tid] = r;

        float4 s;
        s.x = cv[j + 4].x + h * qv[j + 4].x;
        s.y = cv[j + 4].y + h * qv[j + 4].y;
        s.z = cv[j + 4].z + h * qv[j + 4].z;
        s.w = cv[j + 4].w + h * qv[j + 4].w;
        oa[j * BLOCK + tid] = s;
    }
}

extern "C" void kernel_launch(void* const* d_in, const int* in_sizes, int n_in,
                              void* d_out, int out_size, void* d_ws, size_t ws_size,
                              hipStream_t stream) {
    const float* c_iso   = (const float*)d_in[0];
    const float* c_aniso = (const float*)d_in[1];
    const float* q_iso   = (const float*)d_in[2];
    const float* q_aniso = (const float*)d_in[3];
    const float* charge  = (const float*)d_in[4];
    float* out = (float*)d_out;

    const int B = in_sizes[0] / HALF_N;   // 4096

    qp_charge_norm_kernel<<<B, BLOCK, 0, stream>>>(
        c_iso, c_aniso, q_iso, q_aniso, charge, out, B);
}